// Round 1
// 389.291 us; speedup vs baseline: 1.0572x; 1.0572x over previous
//
#include <hip/hip_runtime.h>
#include <hip/hip_bf16.h>

typedef __bf16 bf16x8 __attribute__((ext_vector_type(8)));
typedef float  f32x4  __attribute__((ext_vector_type(4)));

#define BSZ 8192

union BW2 { __bf16 b[2]; unsigned int u; };
union FR  { unsigned int u[4]; bf16x8 v; };

// ---------------- stats0 (9x9 second-moment) + weight prep merged ----------------
// prep: w1 -> w1b [64 oc][128 k], w2 -> w2b [128 oc][256 k], k = d*C + c
__global__ __launch_bounds__(256) void k_stats0(const float* __restrict__ x,
                                                float* __restrict__ part0,
                                                const float* __restrict__ w1,
                                                const float* __restrict__ w2,
                                                __bf16* __restrict__ w1b,
                                                __bf16* __restrict__ w2b) {
    __shared__ float sred[4 * 54];
    const int tid = threadIdx.x;
    {   // merged prep (first 128 blocks' thread-range)
        int t = blockIdx.x * 256 + tid;
        if (t < 8192) {           // w1: 64 oc x 128 k
            int oc = t >> 7, k = t & 127, c = k & 31, d = k >> 5;
            w1b[t] = (__bf16)w1[oc * 128 + c * 4 + d];
        }
        if (t < 32768) {          // w2: 128 oc x 256 k
            int oc = t >> 8, k = t & 255, c = k & 63, d = k >> 6;
            w2b[t] = (__bf16)w2[oc * 256 + c * 4 + d];
        }
    }
    float a[54];
#pragma unroll
    for (int i = 0; i < 54; i++) a[i] = 0.f;
    const int total = BSZ * 784;
    for (int p = blockIdx.x * 256 + tid; p < total; p += gridDim.x * 256) {
        int b = p / 784, pix = p - b * 784;
        int y = pix / 28, xx = pix - y * 28;
        const float* xb = x + (long)b * 784;
        float nv[9];
#pragma unroll
        for (int dy = 0; dy < 3; dy++) {
            int yy = y + dy - 1;
#pragma unroll
            for (int dx = 0; dx < 3; dx++) {
                int x2 = xx + dx - 1;
                nv[dy * 3 + dx] = (yy >= 0 && yy < 28 && x2 >= 0 && x2 < 28) ? xb[yy * 28 + x2] : 0.f;
            }
        }
        int idx = 0;
#pragma unroll
        for (int t2 = 0; t2 < 9; t2++) {
            float vt = nv[t2];
            a[45 + t2] += vt;
#pragma unroll
            for (int u = t2; u < 9; u++) { a[idx] += vt * nv[u]; idx++; }
        }
    }
#pragma unroll
    for (int i = 0; i < 54; i++) {
        float v = a[i];
        v += __shfl_xor(v, 1);  v += __shfl_xor(v, 2);  v += __shfl_xor(v, 4);
        v += __shfl_xor(v, 8);  v += __shfl_xor(v, 16); v += __shfl_xor(v, 32);
        a[i] = v;
    }
    const int l = tid & 63, w = tid >> 6;
    if (l == 0) {
#pragma unroll
        for (int i = 0; i < 54; i++) sred[w * 54 + i] = a[i];
    }
    __syncthreads();
    if (tid < 54)
        part0[blockIdx.x * 64 + tid] = sred[tid] + sred[54 + tid] + sred[108 + tid] + sred[162 + tid];
}

// finalize BN0; emit conv0 bias C0 and conv0-MFMA B-fragments:
//   pass0: k-slot (j,e): patch-row j (0..2), e=2i+par -> tap j*3+i (par 0 = x_hi, 1 = x_lo),
//          both parities carry the same bf16(wf) weight.
//   pass1: e<3 -> tap j*3+e paired with x_hi, weight = fp32 residual wf - bf16(wf).
//   B column n holds channel 2n+hh (interleaved so packed (ch,ch+1) epilogue writes land
//   at the identity slot d*32+c in sAt).
__global__ void k_fin0(const float* __restrict__ part0, const float* __restrict__ w0,
                       const float* __restrict__ g0, const float* __restrict__ be0,
                       float* __restrict__ abc0, __bf16* __restrict__ wcv) {
    __shared__ float red[4 * 54];
    int t = threadIdx.x, c = t & 63, g = t >> 6;
    if (c < 54) {
        float acc = 0.f;
        for (int i = g; i < 1008; i += 4) acc += part0[i * 64 + c];
        red[g * 54 + c] = acc;
    }
    __syncthreads();
    if (t < 54) red[t] = red[t] + red[54 + t] + red[108 + t] + red[162 + t];
    __syncthreads();
    if (t < 32) {
        float wv[9];
#pragma unroll
        for (int tap = 0; tap < 9; tap++) wv[tap] = w0[t * 9 + tap];
        float sum = 0.f, sq = 0.f;
        int idx = 0;
#pragma unroll
        for (int ta = 0; ta < 9; ta++) {
            sum = fmaf(wv[ta], red[45 + ta], sum);
#pragma unroll
            for (int u = ta; u < 9; u++) {
                float coef = (u == ta) ? 1.f : 2.f;
                sq = fmaf(coef * wv[ta] * wv[u], red[idx], sq);
                idx++;
            }
        }
        float cnt = (float)BSZ * 784.f;
        float mean = sum / cnt;
        float var = sq / cnt - mean * mean;
        float A = g0[t] * rsqrtf(var + 1e-5f);
        abc0[288 + t] = be0[t] - mean * A;
        int nn = t >> 1, hh = t & 1;
#pragma unroll
        for (int j = 0; j < 4; j++) {
#pragma unroll
            for (int e = 0; e < 8; e++) {
                float vm = 0.f, vc = 0.f;
                if (j < 3) {
                    int i = e >> 1;
                    if (i < 3) vm = A * wv[j * 3 + i];
                    if (e < 3) {
                        float wfull = A * wv[j * 3 + e];
                        vc = wfull - (float)((__bf16)wfull);
                    }
                }
                wcv[hh * 512 + j * 128 + nn * 8 + e]       = (__bf16)vm;   // pass0
                wcv[(2 + hh) * 512 + j * 128 + nn * 8 + e] = (__bf16)vc;   // pass1 residual
            }
        }
    }
}

// ---------------- conv0 via MFMA (+BN0 folded, ReLU) fused with MFMA conv1 ----------------
// x staged in LDS as packed (x_hi, x_lo) bf16 dwords (hi+lo == fp32-exact x).
// Per tile, wave w owns conv1 tap d=w: each lane fetches its A-fragment straight from xs2
// (3 dword reads = one patch row), runs 4 MFMAs (2 channel halves x {main, weight-residual}),
// then writes bias+ReLU'd bf16 channel pairs into sAt. sAt/w1b/h1 layouts unchanged.
__global__ __launch_bounds__(256, 4) void k_conv01(const float* __restrict__ x,
                                                   const float* __restrict__ abc0,
                                                   const __bf16* __restrict__ wcv,
                                                   const __bf16* __restrict__ w1b,
                                                   __bf16* __restrict__ h1,
                                                   float* __restrict__ part1) {
    __shared__ unsigned int xs2[31 * 30];   // 1-pad border + zero row 30 (chunk j=3 reads land there)
    __shared__ __attribute__((aligned(16))) __bf16 sAt[2][16 * 136];
    const int tid = threadIdx.x;
    const int w = tid >> 6, l = tid & 63, q = l >> 4, n = l & 15;
    const int d1 = w >> 1, d0 = w & 1;
    for (int i = tid; i < 930; i += 256) xs2[i] = 0u;   // border + row30 stay 0 forever
    // hoisted conv0 B-frags + bias (lane: col=n -> channels 2n/2n+1, k-chunk = q)
    bf16x8 bw[2][2];
#pragma unroll
    for (int ps = 0; ps < 2; ps++)
#pragma unroll
        for (int h = 0; h < 2; h++)
            bw[ps][h] = *(const bf16x8*)&wcv[(ps * 2 + h) * 512 + q * 128 + n * 8];
    const float bias0 = abc0[288 + 2 * n];
    const float bias1 = abc0[288 + 2 * n + 1];
    // hoisted conv1 B-frags
    const int oc = w * 16 + n;
    bf16x8 fbv[4];
#pragma unroll
    for (int kc = 0; kc < 4; kc++)
        fbv[kc] = *(const bf16x8*)&w1b[oc * 128 + kc * 32 + q * 8];
    __syncthreads();   // zero-init complete before first staging

    for (int img = 0; img < 4; img++) {
        const int b = blockIdx.x * 4 + img;
        for (int jj = tid; jj < 784; jj += 256) {
            int yy = jj / 28, xx2 = jj - yy * 28;
            float f = x[(long)b * 784 + jj];
            __bf16 hi = (__bf16)f;
            __bf16 lo = (__bf16)(f - (float)hi);
            BW2 pk; pk.b[0] = hi; pk.b[1] = lo;
            xs2[(yy + 1) * 30 + xx2 + 1] = pk.u;
        }
        __syncthreads();   // xs2 ready; also separates prev image's sAt[0] reads from tile-0 writes
        float ssum = 0.f, ssq = 0.f;
        __bf16* hb = h1 + (long)b * 12544 + (q * 4) * 64 + oc;
        for (int mt = 0; mt < 13; mt++) {
            // ---- produce: conv0 MFMA into sAt[mt&1], this wave's tap d ----
            {
                int m = mt * 16 + n;
                int mv = m < 195 ? m : 195;          // clamp pad rows (zeroed at write)
                int my = mv / 14, mx = mv - my * 14;
                int row = 2 * my + d1 + q, col = 2 * mx + d0;   // row <= 30, in bounds
                const unsigned int* p = &xs2[row * 30 + col];
                unsigned int u0 = p[0], u1 = p[1], u2 = p[2];
                FR a0, a1;
                a0.u[0] = u0; a0.u[1] = u1; a0.u[2] = u2; a0.u[3] = 0u;          // (hi,lo) pairs
                a1.u[0] = (u0 & 0xffffu) | (u1 << 16); a1.u[1] = u2 & 0xffffu;   // hi-only, packed
                a1.u[2] = 0u; a1.u[3] = 0u;
                f32x4 ac0 = {bias0, bias0, bias0, bias0};
                f32x4 ac1 = {bias1, bias1, bias1, bias1};
                ac0 = __builtin_amdgcn_mfma_f32_16x16x32_bf16(a0.v, bw[0][0], ac0, 0, 0, 0);
                ac1 = __builtin_amdgcn_mfma_f32_16x16x32_bf16(a0.v, bw[0][1], ac1, 0, 0, 0);
                ac0 = __builtin_amdgcn_mfma_f32_16x16x32_bf16(a1.v, bw[1][0], ac0, 0, 0, 0);
                ac1 = __builtin_amdgcn_mfma_f32_16x16x32_bf16(a1.v, bw[1][1], ac1, 0, 0, 0);
#pragma unroll
                for (int r = 0; r < 4; r++) {
                    int mrow = q * 4 + r;
                    float v0 = fmaxf(ac0[r], 0.f), v1 = fmaxf(ac1[r], 0.f);
                    if (mt * 16 + mrow >= 196) { v0 = 0.f; v1 = 0.f; }
                    BW2 pk; pk.b[0] = (__bf16)v0; pk.b[1] = (__bf16)v1;
                    *(unsigned int*)&sAt[mt & 1][mrow * 136 + w * 32 + 2 * n] = pk.u;
                }
            }
            __syncthreads();
            // ---- consume tile mt: conv1 MFMA ----
            const __bf16* sa = &sAt[mt & 1][n * 136 + q * 8];
            f32x4 acc = {0.f, 0.f, 0.f, 0.f};
#pragma unroll
            for (int kc = 0; kc < 4; kc++) {
                bf16x8 fav = *(const bf16x8*)&sa[kc * 32];
                acc = __builtin_amdgcn_mfma_f32_16x16x32_bf16(fav, fbv[kc], acc, 0, 0, 0);
            }
            bool valid = (mt < 12) | (q == 0);
            __bf16* hp = hb + mt * 16 * 64;
#pragma unroll
            for (int r = 0; r < 4; r++) {
                __bf16 hv = (__bf16)acc[r];
                if (valid) hp[r * 64] = hv;
                float fv = (float)hv;               // padded rows give 0 -> no stat effect
                ssum += fv; ssq += fv * fv;
            }
        }
        ssum += __shfl_xor(ssum, 16); ssum += __shfl_xor(ssum, 32);
        ssq  += __shfl_xor(ssq, 16);  ssq  += __shfl_xor(ssq, 32);
        if (l < 16) {
            part1[(long)oc * BSZ + b] = ssum;
            part1[(long)(64 + oc) * BSZ + b] = ssq;
        }
    }
}

// ---------------- fused per-channel column reduce + BN finalize ----------------
__global__ __launch_bounds__(256) void k_redfin(const float* __restrict__ part,
                                                const float* __restrict__ g,
                                                const float* __restrict__ be,
                                                float* __restrict__ abc,
                                                int C, float cnt) {
    __shared__ float s1[256], s2[256];
    const int c = blockIdx.x, tid = threadIdx.x;
    float a = 0.f, bq = 0.f;
    const float* p1 = part + (long)c * BSZ;
    const float* p2 = part + (long)(C + c) * BSZ;
    for (int i = tid; i < BSZ; i += 256) { a += p1[i]; bq += p2[i]; }
    s1[tid] = a; s2[tid] = bq;
    __syncthreads();
    for (int s = 128; s > 0; s >>= 1) {
        if (tid < s) { s1[tid] += s1[tid + s]; s2[tid] += s2[tid + s]; }
        __syncthreads();
    }
    if (tid == 0) {
        float mean = s1[0] / cnt;
        float var = s2[0] / cnt - mean * mean;
        float A = g[c] * rsqrtf(var + 1e-5f);
        abc[c] = A;
        abc[C + c] = be[c] - mean * A;
    }
}

// ---------------- conv2 MFMA (BN1+ReLU on load), streamed tiles, 4 images/block ----------------
// z2 stores bounced through LDS (zt, stride 136) -> coalesced bf16x8 row stores.
// alias safety per tile mt: z2 writes at elem < (mt+1)*2048; produce(mt+1) loads at elem >= 3584/7168/10752.
__global__ __launch_bounds__(256) void k_conv2s(__bf16* __restrict__ h1,
                                                const __bf16* __restrict__ w2b,
                                                const float* __restrict__ abc1,
                                                float* __restrict__ part2) {
    __shared__ __attribute__((aligned(16))) __bf16 sAt[2][16 * 264];
    __shared__ __attribute__((aligned(16))) __bf16 zt[16 * 136];
    __shared__ float sbn1[128];
    const int tid = threadIdx.x;
    if (tid < 128) sbn1[tid] = abc1[tid];
    const int w = tid >> 6, l = tid & 63, q = l >> 4, n = l & 15;
    bf16x8 fbv[2][8];
#pragma unroll
    for (int ntl = 0; ntl < 2; ntl++) {
        int oc = (2 * w + ntl) * 16 + n;
#pragma unroll
        for (int kc = 0; kc < 8; kc++)
            fbv[ntl][kc] = *(const bf16x8*)&w2b[oc * 256 + kc * 32 + q * 8];
    }
    __syncthreads();   // sbn1 ready

    for (int img = 0; img < 4; img++) {
        const int b = blockIdx.x * 4 + img;
        __bf16* src = h1 + (long)b * 12544;
        float ssum[2] = {0.f, 0.f}, ssq[2] = {0.f, 0.f};
        for (int mt = 0; mt < 4; mt++) {
            // ---- produce tile mt into sAt[mt&1]: 512 chunks, 2 per thread ----
#pragma unroll
            for (int it = 0; it < 2; it++) {
                int idx = it * 256 + tid;
                int rl = idx >> 5, o = (idx & 31) * 8;
                int r = mt * 16 + rl;
                bf16x8 wv;
                if (r < 49) {
                    int d = o >> 6, c = o & 63;
                    int py = r / 7, px = r - py * 7;
                    int msrc = (2 * py + (d >> 1)) * 14 + 2 * px + (d & 1);
                    bf16x8 v = *(const bf16x8*)&src[msrc * 64 + c];
#pragma unroll
                    for (int j = 0; j < 8; j++) {
                        float f = fmaxf((float)v[j] * sbn1[c + j] + sbn1[64 + c + j], 0.f);
                        wv[j] = (__bf16)f;
                    }
                } else {
#pragma unroll
                    for (int j = 0; j < 8; j++) wv[j] = (__bf16)0.0f;
                }
                *(bf16x8*)&sAt[mt & 1][rl * 264 + o] = wv;
            }
            __syncthreads();   // B1: tile ready (also: all prior zt reads precede this in program order)
            // ---- consume tile mt: MFMA -> zt + stats ----
            bf16x8 fav[8];
#pragma unroll
            for (int kc = 0; kc < 8; kc++)
                fav[kc] = *(const bf16x8*)&sAt[mt & 1][n * 264 + kc * 32 + q * 8];
#pragma unroll
            for (int ntl = 0; ntl < 2; ntl++) {
                f32x4 acc = {0.f, 0.f, 0.f, 0.f};
#pragma unroll
                for (int kc = 0; kc < 8; kc++)
                    acc = __builtin_amdgcn_mfma_f32_16x16x32_bf16(fav[kc], fbv[ntl][kc], acc, 0, 0, 0);
#pragma unroll
                for (int rr = 0; rr < 4; rr++) {
                    __bf16 hv = (__bf16)acc[rr];
                    zt[(q * 4 + rr) * 136 + (2 * w + ntl) * 16 + n] = hv;
                    float fv = (float)hv;           // padded rows -> 0
                    ssum[ntl] += fv; ssq[ntl] += fv * fv;
                }
            }
            __syncthreads();   // B2: zt complete
            // ---- coalesced z2 store: 16 rows x 128 oc, one bf16x8 per thread ----
            {
                int row = tid >> 4, o = (tid & 15) * 8;
                int m = mt * 16 + row;
                if (m < 49) {
                    bf16x8 zv = *(const bf16x8*)&zt[row * 136 + o];
                    *(bf16x8*)&src[m * 128 + o] = zv;
                }
            }
        }
#pragma unroll
        for (int ntl = 0; ntl < 2; ntl++) {
            ssum[ntl] += __shfl_xor(ssum[ntl], 16); ssum[ntl] += __shfl_xor(ssum[ntl], 32);
            ssq[ntl]  += __shfl_xor(ssq[ntl], 16);  ssq[ntl]  += __shfl_xor(ssq[ntl], 32);
        }
        if (l < 16) {
#pragma unroll
            for (int ntl = 0; ntl < 2; ntl++) {
                int oc = (2 * w + ntl) * 16 + l;
                part2[(long)oc * BSZ + b] = ssum[ntl];
                part2[(long)(128 + oc) * BSZ + b] = ssq[ntl];
            }
        }
    }
}

// ---------------- light epilogue: BN2 + ReLU + avgpool + FC from z2, 4 images/block ----------------
__global__ __launch_bounds__(256) void k_final(const __bf16* __restrict__ z2,
                                               const float* __restrict__ abc2,
                                               const float* __restrict__ wfc,
                                               const float* __restrict__ bfc,
                                               float* __restrict__ out) {
    __shared__ float sbn2[256];
    __shared__ float pp[16 * 128];
    __shared__ float pooled[128];
    __shared__ float fcred[80];
    const int tid = threadIdx.x;
    sbn2[tid] = abc2[tid];
    __syncthreads();
    const int g = tid & 15, c0 = g * 8, rg = tid >> 4;
    for (int img = 0; img < 4; img++) {
        const int b = blockIdx.x * 4 + img;
        const __bf16* src = z2 + (long)b * 12544;
        float acc[8];
#pragma unroll
        for (int q = 0; q < 8; q++) acc[q] = 0.f;
        for (int rr = rg; rr < 49; rr += 16) {
            bf16x8 v = *(const bf16x8*)&src[rr * 128 + c0];
#pragma unroll
            for (int q = 0; q < 8; q++) {
                float f = fmaxf((float)v[q] * sbn2[c0 + q] + sbn2[128 + c0 + q], 0.f);
                acc[q] += f;
            }
        }
        *(f32x4*)&pp[rg * 128 + c0]     = *(f32x4*)&acc[0];
        *(f32x4*)&pp[rg * 128 + c0 + 4] = *(f32x4*)&acc[4];
        __syncthreads();
        if (tid < 128) {
            float s = 0.f;
#pragma unroll
            for (int r = 0; r < 16; r++) s += pp[r * 128 + tid];
            pooled[tid] = s * (1.f / 49.f);
        }
        __syncthreads();
        if (tid < 80) {
            int o = tid >> 3, s = tid & 7;
            float a = 0.f;
#pragma unroll
            for (int j = 0; j < 16; j++) a = fmaf(pooled[s * 16 + j], wfc[o * 128 + s * 16 + j], a);
            fcred[tid] = a;
        }
        __syncthreads();
        if (tid < 10) {
            float a = bfc[tid];
#pragma unroll
            for (int s = 0; s < 8; s++) a += fcred[tid * 8 + s];
            out[(long)b * 10 + tid] = a;
        }
    }
}

extern "C" void kernel_launch(void* const* d_in, const int* in_sizes, int n_in,
                              void* d_out, int out_size, void* d_ws, size_t ws_size,
                              hipStream_t stream) {
    const float* x   = (const float*)d_in[0];
    const float* w0  = (const float*)d_in[1];
    const float* g0  = (const float*)d_in[3];
    const float* be0 = (const float*)d_in[4];
    const float* w1  = (const float*)d_in[5];
    const float* g1  = (const float*)d_in[7];
    const float* be1 = (const float*)d_in[8];
    const float* w2  = (const float*)d_in[9];
    const float* g2  = (const float*)d_in[11];
    const float* be2 = (const float*)d_in[12];
    const float* wfc = (const float*)d_in[13];
    const float* bfc = (const float*)d_in[14];
    float* out = (float*)d_out;

    float* ws    = (float*)d_ws;
    float* part0 = ws;                       // 1008*64 used; tail holds wcv
    __bf16* wcv  = (__bf16*)(part0 + 1008 * 64);  // 2048 bf16 = 1024 floats -> ends at part0+65536
    float* abc0  = part0 + 1024 * 64;        // 320 (bias C0 at [288..320))
    float* part1 = abc0 + 320;               // 128*8192
    float* abc1  = part1 + 128 * BSZ;        // 128
    float* part2 = abc1 + 128;               // 256*8192
    float* abc2  = part2 + 256 * BSZ;        // 256
    __bf16* w1b  = (__bf16*)(abc2 + 256);    // 8192
    __bf16* w2b  = w1b + 8192;               // 32768
    __bf16* h1   = w2b + 32768;              // 8192*12544 bf16 (~205 MB); z2 aliased per-image

    k_stats0<<<dim3(1008), dim3(256), 0, stream>>>(x, part0, w1, w2, w1b, w2b);
    k_fin0<<<dim3(1), dim3(256), 0, stream>>>(part0, w0, g0, be0, abc0, wcv);
    k_conv01<<<dim3(BSZ / 4), dim3(256), 0, stream>>>(x, abc0, wcv, w1b, h1, part1);
    k_redfin<<<dim3(64), dim3(256), 0, stream>>>(part1, g1, be1, abc1, 64, (float)(BSZ * 196));
    k_conv2s<<<dim3(BSZ / 4), dim3(256), 0, stream>>>(h1, w2b, abc1, part2);
    k_redfin<<<dim3(128), dim3(256), 0, stream>>>(part2, g2, be2, abc2, 128, (float)(BSZ * 49));
    k_final<<<dim3(BSZ / 4), dim3(256), 0, stream>>>(h1, abc2, wfc, bfc, out);
}

// Round 2
// 388.314 us; speedup vs baseline: 1.0599x; 1.0025x over previous
//
#include <hip/hip_runtime.h>
#include <hip/hip_bf16.h>

typedef __bf16 bf16x8 __attribute__((ext_vector_type(8)));
typedef float  f32x4  __attribute__((ext_vector_type(4)));

#define BSZ 8192

union BW2 { __bf16 b[2]; unsigned int u; };
union FR  { unsigned int u[4]; bf16x8 v; };

// ---------------- stats0 (9x9 second-moment) + weight prep merged ----------------
// prep: w1 -> w1b [64 oc][128 k], w2 -> w2b [128 oc][256 k], k = d*C + c
__global__ __launch_bounds__(256) void k_stats0(const float* __restrict__ x,
                                                float* __restrict__ part0,
                                                const float* __restrict__ w1,
                                                const float* __restrict__ w2,
                                                __bf16* __restrict__ w1b,
                                                __bf16* __restrict__ w2b) {
    __shared__ float sred[4 * 54];
    const int tid = threadIdx.x;
    {   // merged prep (first 128 blocks' thread-range)
        int t = blockIdx.x * 256 + tid;
        if (t < 8192) {           // w1: 64 oc x 128 k
            int oc = t >> 7, k = t & 127, c = k & 31, d = k >> 5;
            w1b[t] = (__bf16)w1[oc * 128 + c * 4 + d];
        }
        if (t < 32768) {          // w2: 128 oc x 256 k
            int oc = t >> 8, k = t & 255, c = k & 63, d = k >> 6;
            w2b[t] = (__bf16)w2[oc * 256 + c * 4 + d];
        }
    }
    float a[54];
#pragma unroll
    for (int i = 0; i < 54; i++) a[i] = 0.f;
    const int total = BSZ * 784;
    for (int p = blockIdx.x * 256 + tid; p < total; p += gridDim.x * 256) {
        int b = p / 784, pix = p - b * 784;
        int y = pix / 28, xx = pix - y * 28;
        const float* xb = x + (long)b * 784;
        float nv[9];
#pragma unroll
        for (int dy = 0; dy < 3; dy++) {
            int yy = y + dy - 1;
#pragma unroll
            for (int dx = 0; dx < 3; dx++) {
                int x2 = xx + dx - 1;
                nv[dy * 3 + dx] = (yy >= 0 && yy < 28 && x2 >= 0 && x2 < 28) ? xb[yy * 28 + x2] : 0.f;
            }
        }
        int idx = 0;
#pragma unroll
        for (int t2 = 0; t2 < 9; t2++) {
            float vt = nv[t2];
            a[45 + t2] += vt;
#pragma unroll
            for (int u = t2; u < 9; u++) { a[idx] += vt * nv[u]; idx++; }
        }
    }
#pragma unroll
    for (int i = 0; i < 54; i++) {
        float v = a[i];
        v += __shfl_xor(v, 1);  v += __shfl_xor(v, 2);  v += __shfl_xor(v, 4);
        v += __shfl_xor(v, 8);  v += __shfl_xor(v, 16); v += __shfl_xor(v, 32);
        a[i] = v;
    }
    const int l = tid & 63, w = tid >> 6;
    if (l == 0) {
#pragma unroll
        for (int i = 0; i < 54; i++) sred[w * 54 + i] = a[i];
    }
    __syncthreads();
    if (tid < 54)
        part0[blockIdx.x * 64 + tid] = sred[tid] + sred[54 + tid] + sred[108 + tid] + sred[162 + tid];
}

// finalize BN0; emit conv0 bias C0 and conv0-MFMA B-fragments:
//   pass0: k-slot (j,e): patch-row j (0..2), e=2i+par -> tap j*3+i (par 0 = x_hi, 1 = x_lo),
//          both parities carry the same bf16(wf) weight.
//   pass1: e<3 -> tap j*3+e paired with x_hi, weight = fp32 residual wf - bf16(wf).
//   B column n holds channel 2n+hh.
__global__ void k_fin0(const float* __restrict__ part0, const float* __restrict__ w0,
                       const float* __restrict__ g0, const float* __restrict__ be0,
                       float* __restrict__ abc0, __bf16* __restrict__ wcv) {
    __shared__ float red[4 * 54];
    int t = threadIdx.x, c = t & 63, g = t >> 6;
    if (c < 54) {
        float acc = 0.f;
        for (int i = g; i < 1008; i += 4) acc += part0[i * 64 + c];
        red[g * 54 + c] = acc;
    }
    __syncthreads();
    if (t < 54) red[t] = red[t] + red[54 + t] + red[108 + t] + red[162 + t];
    __syncthreads();
    if (t < 32) {
        float wv[9];
#pragma unroll
        for (int tap = 0; tap < 9; tap++) wv[tap] = w0[t * 9 + tap];
        float sum = 0.f, sq = 0.f;
        int idx = 0;
#pragma unroll
        for (int ta = 0; ta < 9; ta++) {
            sum = fmaf(wv[ta], red[45 + ta], sum);
#pragma unroll
            for (int u = ta; u < 9; u++) {
                float coef = (u == ta) ? 1.f : 2.f;
                sq = fmaf(coef * wv[ta] * wv[u], red[idx], sq);
                idx++;
            }
        }
        float cnt = (float)BSZ * 784.f;
        float mean = sum / cnt;
        float var = sq / cnt - mean * mean;
        float A = g0[t] * rsqrtf(var + 1e-5f);
        abc0[288 + t] = be0[t] - mean * A;
        int nn = t >> 1, hh = t & 1;
#pragma unroll
        for (int j = 0; j < 4; j++) {
#pragma unroll
            for (int e = 0; e < 8; e++) {
                float vm = 0.f, vc = 0.f;
                if (j < 3) {
                    int i = e >> 1;
                    if (i < 3) vm = A * wv[j * 3 + i];
                    if (e < 3) {
                        float wfull = A * wv[j * 3 + e];
                        vc = wfull - (float)((__bf16)wfull);
                    }
                }
                wcv[hh * 512 + j * 128 + nn * 8 + e]       = (__bf16)vm;   // pass0
                wcv[(2 + hh) * 512 + j * 128 + nn * 8 + e] = (__bf16)vc;   // pass1 residual
            }
        }
    }
}

// ---------------- conv0 (MFMA, BN0 folded, ReLU) + conv1 (MFMA), 1 wave = 1 image ----------------
// Barrier-free: each wave owns a full image; producer->consumer data flows through per-block
// (= per-wave) LDS, relying on the in-order DS pipe (no __syncthreads anywhere).
// Producer: all 4 conv1 taps (16 MFMA/tile). Consumer: all 64 oc (16 MFMA/tile, fbv = 64 VGPR).
// Stats taken on f32 accumulators directly (pad rows contribute exact 0).
__global__ __launch_bounds__(64, 3) void k_conv01(const float* __restrict__ x,
                                                  const float* __restrict__ abc0,
                                                  const __bf16* __restrict__ wcv,
                                                  const __bf16* __restrict__ w1b,
                                                  __bf16* __restrict__ h1,
                                                  float* __restrict__ part1) {
    __shared__ unsigned int xs2[31 * 30];   // packed (x_hi,x_lo) bf16 pairs; border + row30 stay 0
    __shared__ __attribute__((aligned(16))) __bf16 sAt[16 * 136];
    const int l = threadIdx.x;              // 0..63 (one wave)
    const int q = l >> 4, n = l & 15;
    const int b = blockIdx.x;
    for (int i = l; i < 930; i += 64) xs2[i] = 0u;
    // conv0 B-frags + bias (lane: col=n -> channels 2n/2n+1, k-chunk = q)
    bf16x8 bw[2][2];
#pragma unroll
    for (int ps = 0; ps < 2; ps++)
#pragma unroll
        for (int h = 0; h < 2; h++)
            bw[ps][h] = *(const bf16x8*)&wcv[(ps * 2 + h) * 512 + q * 128 + n * 8];
    const float bias0 = abc0[288 + 2 * n];
    const float bias1 = abc0[288 + 2 * n + 1];
    // conv1 B-frags: all 4 oc-groups (g*16+n)
    bf16x8 fbv[4][4];
#pragma unroll
    for (int g = 0; g < 4; g++)
#pragma unroll
        for (int kc = 0; kc < 4; kc++)
            fbv[g][kc] = *(const bf16x8*)&w1b[(g * 16 + n) * 128 + kc * 32 + q * 8];

    // stage image (own wave only; DS in-order => no barrier)
    for (int jj = l; jj < 784; jj += 64) {
        int yy = jj / 28, xx2 = jj - yy * 28;
        float f = x[(long)b * 784 + jj];
        __bf16 hi = (__bf16)f;
        __bf16 lo = (__bf16)(f - (float)hi);
        BW2 pk; pk.b[0] = hi; pk.b[1] = lo;
        xs2[(yy + 1) * 30 + xx2 + 1] = pk.u;
    }

    float ssum[4], ssq[4];
#pragma unroll
    for (int g = 0; g < 4; g++) { ssum[g] = 0.f; ssq[g] = 0.f; }
    // incremental divmod: (my,mx) = divmod(mt*16 + n, 14)
    int my = (n >= 14) ? 1 : 0;
    int mx = n - my * 14;
    __bf16* hb = h1 + (long)b * 12544 + q * 256 + n;

    auto produce = [&](int mt, bool last) {
        int myv = my, mxv = mx;
        if (last) {           // lanes n>=4 are pad A-rows: clamp to position 195 (valid memory)
            bool pad = (n >= 4);
            myv = pad ? 13 : my;
            mxv = pad ? 13 : mx;
        }
        const int rowb = 2 * myv + q, colb = 2 * mxv;
#pragma unroll
        for (int t = 0; t < 4; t++) {
            const int d1 = t >> 1, d0 = t & 1;
            const unsigned int* p = &xs2[(rowb + d1) * 30 + colb + d0];
            unsigned int u0 = p[0], u1 = p[1], u2 = p[2];
            FR a0, a1;
            a0.u[0] = u0; a0.u[1] = u1; a0.u[2] = u2; a0.u[3] = 0u;          // (hi,lo) pairs
            a1.u[0] = (u0 & 0xffffu) | (u1 << 16); a1.u[1] = u2 & 0xffffu;   // hi-only, packed
            a1.u[2] = 0u; a1.u[3] = 0u;
            f32x4 ac0 = {bias0, bias0, bias0, bias0};
            f32x4 ac1 = {bias1, bias1, bias1, bias1};
            ac0 = __builtin_amdgcn_mfma_f32_16x16x32_bf16(a0.v, bw[0][0], ac0, 0, 0, 0);
            ac1 = __builtin_amdgcn_mfma_f32_16x16x32_bf16(a0.v, bw[0][1], ac1, 0, 0, 0);
            ac0 = __builtin_amdgcn_mfma_f32_16x16x32_bf16(a1.v, bw[1][0], ac0, 0, 0, 0);
            ac1 = __builtin_amdgcn_mfma_f32_16x16x32_bf16(a1.v, bw[1][1], ac1, 0, 0, 0);
#pragma unroll
            for (int r = 0; r < 4; r++) {
                float v0 = fmaxf(ac0[r], 0.f), v1 = fmaxf(ac1[r], 0.f);
                if (last && q != 0) { v0 = 0.f; v1 = 0.f; }   // zero pad C-rows (q*4+r >= 4)
                BW2 pk; pk.b[0] = (__bf16)v0; pk.b[1] = (__bf16)v1;
                *(unsigned int*)&sAt[(q * 4 + r) * 136 + t * 32 + 2 * n] = pk.u;
            }
        }
    };

    for (int mt = 0; mt < 13; mt++) {
        if (mt < 12) produce(mt, false); else produce(mt, true);
        // next-tile (my,mx): m += 16 = 14 + 2
        mx += 2; my += 1;
        if (mx >= 14) { mx -= 14; my += 1; }
        // ---- consume tile mt: conv1 MFMA over all 4 oc-groups ----
        bf16x8 fav[4];
        const __bf16* sa = &sAt[n * 136 + q * 8];
#pragma unroll
        for (int kc = 0; kc < 4; kc++) fav[kc] = *(const bf16x8*)&sa[kc * 32];
        const bool valid = (mt < 12) | (q == 0);
        __builtin_amdgcn_s_setprio(1);
#pragma unroll
        for (int g = 0; g < 4; g++) {
            f32x4 acc = {0.f, 0.f, 0.f, 0.f};
#pragma unroll
            for (int kc = 0; kc < 4; kc++)
                acc = __builtin_amdgcn_mfma_f32_16x16x32_bf16(fav[kc], fbv[g][kc], acc, 0, 0, 0);
#pragma unroll
            for (int r = 0; r < 4; r++) {
                if (valid) hb[mt * 1024 + r * 64 + g * 16] = (__bf16)acc[r];
                ssum[g] += acc[r]; ssq[g] += acc[r] * acc[r];   // pad rows: acc == 0 exactly
            }
        }
        __builtin_amdgcn_s_setprio(0);
    }
#pragma unroll
    for (int g = 0; g < 4; g++) {
        ssum[g] += __shfl_xor(ssum[g], 16); ssum[g] += __shfl_xor(ssum[g], 32);
        ssq[g]  += __shfl_xor(ssq[g], 16);  ssq[g]  += __shfl_xor(ssq[g], 32);
    }
    if (l < 16) {
#pragma unroll
        for (int g = 0; g < 4; g++) {
            part1[(long)(g * 16 + l) * BSZ + b] = ssum[g];
            part1[(long)(64 + g * 16 + l) * BSZ + b] = ssq[g];
        }
    }
}

// ---------------- fused per-channel column reduce + BN finalize ----------------
__global__ __launch_bounds__(256) void k_redfin(const float* __restrict__ part,
                                                const float* __restrict__ g,
                                                const float* __restrict__ be,
                                                float* __restrict__ abc,
                                                int C, float cnt) {
    __shared__ float s1[256], s2[256];
    const int c = blockIdx.x, tid = threadIdx.x;
    float a = 0.f, bq = 0.f;
    const float* p1 = part + (long)c * BSZ;
    const float* p2 = part + (long)(C + c) * BSZ;
    for (int i = tid; i < BSZ; i += 256) { a += p1[i]; bq += p2[i]; }
    s1[tid] = a; s2[tid] = bq;
    __syncthreads();
    for (int s = 128; s > 0; s >>= 1) {
        if (tid < s) { s1[tid] += s1[tid + s]; s2[tid] += s2[tid + s]; }
        __syncthreads();
    }
    if (tid == 0) {
        float mean = s1[0] / cnt;
        float var = s2[0] / cnt - mean * mean;
        float A = g[c] * rsqrtf(var + 1e-5f);
        abc[c] = A;
        abc[C + c] = be[c] - mean * A;
    }
}

// ---------------- conv2 MFMA (BN1+ReLU on load), streamed tiles, 4 images/block ----------------
// oc remap: oc = w*32 + 2n + ntl => a lane's two accumulators are ADJACENT channels ->
// packed dword zt writes (4 instead of 8 scalar b16; 2-way bank aliasing = free).
// Stats on f32 accumulators directly. z2 stores via zt bounce (coalesced bf16x8 rows).
// alias safety per tile mt: z2 writes at elem < (mt+1)*2048; produce(mt+1) loads at elem >= 3584/7168/10752.
__global__ __launch_bounds__(256) void k_conv2s(__bf16* __restrict__ h1,
                                                const __bf16* __restrict__ w2b,
                                                const float* __restrict__ abc1,
                                                float* __restrict__ part2) {
    __shared__ __attribute__((aligned(16))) __bf16 sAt[2][16 * 264];
    __shared__ __attribute__((aligned(16))) __bf16 zt[16 * 136];
    __shared__ float sbn1[128];
    const int tid = threadIdx.x;
    if (tid < 128) sbn1[tid] = abc1[tid];
    const int w = tid >> 6, l = tid & 63, q = l >> 4, n = l & 15;
    bf16x8 fbv[2][8];
#pragma unroll
    for (int ntl = 0; ntl < 2; ntl++) {
        int oc = w * 32 + 2 * n + ntl;
#pragma unroll
        for (int kc = 0; kc < 8; kc++)
            fbv[ntl][kc] = *(const bf16x8*)&w2b[oc * 256 + kc * 32 + q * 8];
    }
    __syncthreads();   // sbn1 ready

    for (int img = 0; img < 4; img++) {
        const int b = blockIdx.x * 4 + img;
        __bf16* src = h1 + (long)b * 12544;
        float ssum[2] = {0.f, 0.f}, ssq[2] = {0.f, 0.f};
        for (int mt = 0; mt < 4; mt++) {
            // ---- produce tile mt into sAt[mt&1]: 512 chunks, 2 per thread ----
#pragma unroll
            for (int it = 0; it < 2; it++) {
                int idx = it * 256 + tid;
                int rl = idx >> 5, o = (idx & 31) * 8;
                int r = mt * 16 + rl;
                bf16x8 wv;
                if (r < 49) {
                    int d = o >> 6, c = o & 63;
                    int py = r / 7, px = r - py * 7;
                    int msrc = (2 * py + (d >> 1)) * 14 + 2 * px + (d & 1);
                    bf16x8 v = *(const bf16x8*)&src[msrc * 64 + c];
#pragma unroll
                    for (int j = 0; j < 8; j++) {
                        float f = fmaxf((float)v[j] * sbn1[c + j] + sbn1[64 + c + j], 0.f);
                        wv[j] = (__bf16)f;
                    }
                } else {
#pragma unroll
                    for (int j = 0; j < 8; j++) wv[j] = (__bf16)0.0f;
                }
                *(bf16x8*)&sAt[mt & 1][rl * 264 + o] = wv;
            }
            __syncthreads();   // B1: tile ready (also: all prior zt reads precede this in program order)
            // ---- consume tile mt: MFMA -> zt (packed pairs) + f32 stats ----
            bf16x8 fav[8];
#pragma unroll
            for (int kc = 0; kc < 8; kc++)
                fav[kc] = *(const bf16x8*)&sAt[mt & 1][n * 264 + kc * 32 + q * 8];
            f32x4 accA = {0.f, 0.f, 0.f, 0.f}, accB = {0.f, 0.f, 0.f, 0.f};
#pragma unroll
            for (int kc = 0; kc < 8; kc++) {
                accA = __builtin_amdgcn_mfma_f32_16x16x32_bf16(fav[kc], fbv[0][kc], accA, 0, 0, 0);
                accB = __builtin_amdgcn_mfma_f32_16x16x32_bf16(fav[kc], fbv[1][kc], accB, 0, 0, 0);
            }
#pragma unroll
            for (int rr = 0; rr < 4; rr++) {
                BW2 pk; pk.b[0] = (__bf16)accA[rr]; pk.b[1] = (__bf16)accB[rr];
                *(unsigned int*)&zt[(q * 4 + rr) * 136 + w * 32 + 2 * n] = pk.u;
                ssum[0] += accA[rr]; ssq[0] += accA[rr] * accA[rr];   // pad rows -> 0
                ssum[1] += accB[rr]; ssq[1] += accB[rr] * accB[rr];
            }
            __syncthreads();   // B2: zt complete
            // ---- coalesced z2 store: 16 rows x 128 oc, one bf16x8 per thread ----
            {
                int row = tid >> 4, o = (tid & 15) * 8;
                int m = mt * 16 + row;
                if (m < 49) {
                    bf16x8 zv = *(const bf16x8*)&zt[row * 136 + o];
                    *(bf16x8*)&src[m * 128 + o] = zv;
                }
            }
        }
#pragma unroll
        for (int ntl = 0; ntl < 2; ntl++) {
            ssum[ntl] += __shfl_xor(ssum[ntl], 16); ssum[ntl] += __shfl_xor(ssum[ntl], 32);
            ssq[ntl]  += __shfl_xor(ssq[ntl], 16);  ssq[ntl]  += __shfl_xor(ssq[ntl], 32);
        }
        if (l < 16) {
#pragma unroll
            for (int ntl = 0; ntl < 2; ntl++) {
                int oc = w * 32 + 2 * l + ntl;
                part2[(long)oc * BSZ + b] = ssum[ntl];
                part2[(long)(128 + oc) * BSZ + b] = ssq[ntl];
            }
        }
    }
}

// ---------------- light epilogue: BN2 + ReLU + avgpool + FC from z2, 4 images/block ----------------
__global__ __launch_bounds__(256) void k_final(const __bf16* __restrict__ z2,
                                               const float* __restrict__ abc2,
                                               const float* __restrict__ wfc,
                                               const float* __restrict__ bfc,
                                               float* __restrict__ out) {
    __shared__ float sbn2[256];
    __shared__ float pp[16 * 128];
    __shared__ float pooled[128];
    __shared__ float fcred[80];
    const int tid = threadIdx.x;
    sbn2[tid] = abc2[tid];
    __syncthreads();
    const int g = tid & 15, c0 = g * 8, rg = tid >> 4;
    for (int img = 0; img < 4; img++) {
        const int b = blockIdx.x * 4 + img;
        const __bf16* src = z2 + (long)b * 12544;
        float acc[8];
#pragma unroll
        for (int q = 0; q < 8; q++) acc[q] = 0.f;
        for (int rr = rg; rr < 49; rr += 16) {
            bf16x8 v = *(const bf16x8*)&src[rr * 128 + c0];
#pragma unroll
            for (int q = 0; q < 8; q++) {
                float f = fmaxf((float)v[q] * sbn2[c0 + q] + sbn2[128 + c0 + q], 0.f);
                acc[q] += f;
            }
        }
        *(f32x4*)&pp[rg * 128 + c0]     = *(f32x4*)&acc[0];
        *(f32x4*)&pp[rg * 128 + c0 + 4] = *(f32x4*)&acc[4];
        __syncthreads();
        if (tid < 128) {
            float s = 0.f;
#pragma unroll
            for (int r = 0; r < 16; r++) s += pp[r * 128 + tid];
            pooled[tid] = s * (1.f / 49.f);
        }
        __syncthreads();
        if (tid < 80) {
            int o = tid >> 3, s = tid & 7;
            float a = 0.f;
#pragma unroll
            for (int j = 0; j < 16; j++) a = fmaf(pooled[s * 16 + j], wfc[o * 128 + s * 16 + j], a);
            fcred[tid] = a;
        }
        __syncthreads();
        if (tid < 10) {
            float a = bfc[tid];
#pragma unroll
            for (int s = 0; s < 8; s++) a += fcred[tid * 8 + s];
            out[(long)b * 10 + tid] = a;
        }
    }
}

extern "C" void kernel_launch(void* const* d_in, const int* in_sizes, int n_in,
                              void* d_out, int out_size, void* d_ws, size_t ws_size,
                              hipStream_t stream) {
    const float* x   = (const float*)d_in[0];
    const float* w0  = (const float*)d_in[1];
    const float* g0  = (const float*)d_in[3];
    const float* be0 = (const float*)d_in[4];
    const float* w1  = (const float*)d_in[5];
    const float* g1  = (const float*)d_in[7];
    const float* be1 = (const float*)d_in[8];
    const float* w2  = (const float*)d_in[9];
    const float* g2  = (const float*)d_in[11];
    const float* be2 = (const float*)d_in[12];
    const float* wfc = (const float*)d_in[13];
    const float* bfc = (const float*)d_in[14];
    float* out = (float*)d_out;

    float* ws    = (float*)d_ws;
    float* part0 = ws;                       // 1008*64 used; tail holds wcv
    __bf16* wcv  = (__bf16*)(part0 + 1008 * 64);  // 2048 bf16 = 1024 floats -> ends at part0+65536
    float* abc0  = part0 + 1024 * 64;        // 320 (bias C0 at [288..320))
    float* part1 = abc0 + 320;               // 128*8192
    float* abc1  = part1 + 128 * BSZ;        // 128
    float* part2 = abc1 + 128;               // 256*8192
    float* abc2  = part2 + 256 * BSZ;        // 256
    __bf16* w1b  = (__bf16*)(abc2 + 256);    // 8192
    __bf16* w2b  = w1b + 8192;               // 32768
    __bf16* h1   = w2b + 32768;              // 8192*12544 bf16 (~205 MB); z2 aliased per-image

    k_stats0<<<dim3(1008), dim3(256), 0, stream>>>(x, part0, w1, w2, w1b, w2b);
    k_fin0<<<dim3(1), dim3(256), 0, stream>>>(part0, w0, g0, be0, abc0, wcv);
    k_conv01<<<dim3(BSZ), dim3(64), 0, stream>>>(x, abc0, wcv, w1b, h1, part1);
    k_redfin<<<dim3(64), dim3(256), 0, stream>>>(part1, g1, be1, abc1, 64, (float)(BSZ * 196));
    k_conv2s<<<dim3(BSZ / 4), dim3(256), 0, stream>>>(h1, w2b, abc1, part2);
    k_redfin<<<dim3(128), dim3(256), 0, stream>>>(part2, g2, be2, abc2, 128, (float)(BSZ * 49));
    k_final<<<dim3(BSZ / 4), dim3(256), 0, stream>>>(h1, abc2, wfc, bfc, out);
}